// Round 4
// baseline (1467.105 us; speedup 1.0000x reference)
//
#include <hip/hip_runtime.h>

// ---------------------------------------------------------------------------
// HeteroFraudGNN on MI355X — round 4: latency-bound fix.
// k_fused redesign: 512 threads / 128-row tile, VGPR<=64 -> 32 waves/CU
// (4 blocks x 8 waves), dense-GEMM overlapped with gather (issued before the
// stage barrier), 2-pass gather stage (facc[16]) to hold the register cap.
//   stage:  LDS A1[128][128]f16 = seg_mean(SRC via CSR), XOR-swizzled
//   early:  dense A-frags loaded at kernel entry (overlap with gather)
//   mfma:   acc = DENSE @ BTr   (pre-barrier, regs+L2 only)
//         + A1(LDS) @ BTl       (post-barrier)
//   epi:    bn/relu -> LDS out-tile -> coalesced f16x8 stores
// k_mlp gets the same 128-row/512-thread treatment.
// ---------------------------------------------------------------------------

#define NUv   100000
#define NTv   400000
#define Ev    400000
#define Hv    128
#define NLv   3
#define HID2v 64
#define EPSv  1e-5f

typedef _Float16 h16;
typedef __attribute__((ext_vector_type(8))) _Float16 f16x8;
typedef __attribute__((ext_vector_type(4))) float    f32x4;

#define WS_NEED (280u * 1024u * 1024u)
__device__ __attribute__((aligned(256))) static unsigned char g_ws[WS_NEED];

__device__ __forceinline__ int imin(int a, int b) { return a < b ? a : b; }

// ---------------------------------------------------------------- CSR build
__global__ __launch_bounds__(256) void k_count(const int* __restrict__ d0,
                                               const int* __restrict__ d1,
                                               int* __restrict__ c0,
                                               int* __restrict__ c1, int e) {
  int t = blockIdx.x * 256 + threadIdx.x;
  if (t < e) {
    atomicAdd(c0 + d0[t], 1);
    atomicAdd(c1 + d1[t], 1);
  }
}

__global__ __launch_bounds__(256) void k_blocksum(const int* __restrict__ cnt,
                                                  int* __restrict__ bs, int n) {
  __shared__ int red[256];
  int base = blockIdx.x * 2048 + threadIdx.x * 8;
  int s = 0;
#pragma unroll
  for (int j = 0; j < 8; j++) {
    int p = base + j;
    if (p < n) s += cnt[p];
  }
  red[threadIdx.x] = s;
  __syncthreads();
  for (int st = 128; st > 0; st >>= 1) {
    if (threadIdx.x < st) red[threadIdx.x] += red[threadIdx.x + st];
    __syncthreads();
  }
  if (threadIdx.x == 0) bs[blockIdx.x] = red[0];
}

__global__ __launch_bounds__(256) void k_scansmall(int* __restrict__ bs, int g) {
  __shared__ int lds[256];
  int t = threadIdx.x;
  int v = (t < g) ? bs[t] : 0;
  lds[t] = v;
  __syncthreads();
  for (int st = 1; st < 256; st <<= 1) {
    int x = (t >= st) ? lds[t - st] : 0;
    __syncthreads();
    lds[t] += x;
    __syncthreads();
  }
  if (t < g) bs[t] = lds[t] - v;  // exclusive
}

__global__ __launch_bounds__(256) void k_scanfinal(const int* __restrict__ cnt,
                                                   const int* __restrict__ bs,
                                                   int* __restrict__ off,
                                                   int* __restrict__ cur, int n) {
  __shared__ int lds[256];
  int t = threadIdx.x;
  int base = blockIdx.x * 2048 + t * 8;
  int v[8], pre[8];
  int tsum = 0;
#pragma unroll
  for (int j = 0; j < 8; j++) {
    int p = base + j;
    v[j] = (p < n) ? cnt[p] : 0;
    pre[j] = tsum;
    tsum += v[j];
  }
  lds[t] = tsum;
  __syncthreads();
  for (int st = 1; st < 256; st <<= 1) {
    int x = (t >= st) ? lds[t - st] : 0;
    __syncthreads();
    lds[t] += x;
    __syncthreads();
  }
  int texcl = lds[t] - tsum;
  int boff = bs[blockIdx.x];
#pragma unroll
  for (int j = 0; j < 8; j++) {
    int p = base + j;
    if (p < n) {
      int o = boff + texcl + pre[j];
      off[p] = o;
      cur[p] = o;
      if (p == n - 1) off[n] = o + v[j];
    }
  }
}

__global__ __launch_bounds__(256) void k_fill(const int* __restrict__ s0,
                                              const int* __restrict__ d0,
                                              const int* __restrict__ s1,
                                              const int* __restrict__ d1,
                                              int* __restrict__ cur0,
                                              int* __restrict__ cur1,
                                              int* __restrict__ ss0,
                                              int* __restrict__ ss1, int e) {
  int t = blockIdx.x * 256 + threadIdx.x;
  if (t < e) {
    int p = atomicAdd(cur0 + d0[t], 1);
    ss0[p] = s0[t];
    int q = atomicAdd(cur1 + d1[t], 1);
    ss1[q] = s1[t];
  }
}

// ------------------------------------------------------- weight / bn prep
__global__ __launch_bounds__(256) void k_wt(const float* __restrict__ Wl,
                                            const float* __restrict__ Wr,
                                            const float* __restrict__ W1,
                                            h16* __restrict__ WlT,
                                            h16* __restrict__ WrT,
                                            h16* __restrict__ W1T) {
  int t = blockIdx.x * 256 + threadIdx.x;
  const int NW = NLv * 2 * Hv * Hv;  // 196608
  if (t < NW) {
    int mat = t / (Hv * Hv);
    int n = (t / Hv) % Hv;
    int k = t % Hv;
    WlT[t] = (h16)Wl[(size_t)mat * Hv * Hv + (size_t)k * Hv + n];
    WrT[t] = (h16)Wr[(size_t)mat * Hv * Hv + (size_t)k * Hv + n];
  } else if (t < NW + HID2v * Hv) {
    int u = t - NW;
    int n = u / Hv;
    int k = u % Hv;
    W1T[u] = (h16)W1[(size_t)k * HID2v + n];
  }
}

__global__ __launch_bounds__(256) void k_bn(const float* __restrict__ g,
                                            const float* __restrict__ b,
                                            const float* __restrict__ m,
                                            const float* __restrict__ v,
                                            float* __restrict__ sc,
                                            float* __restrict__ sh) {
  int t = blockIdx.x * 256 + threadIdx.x;
  if (t < NLv * 2 * Hv) {
    float inv = rsqrtf(v[t] + EPSv);
    float s = g[t] * inv;
    sc[t] = s;
    sh[t] = b[t] - m[t] * s;
  }
}

// ------------------------------------------------------------- embeddings
__global__ __launch_bounds__(256) void k_embed(const int* __restrict__ xu,
                                               const int* __restrict__ xt,
                                               const float* __restrict__ eu,
                                               const float* __restrict__ et,
                                               h16* __restrict__ hu,
                                               h16* __restrict__ ht) {
  int t = blockIdx.x * 256 + threadIdx.x;
  int row = t >> 4;
  int c = (t & 15) * 8;
  if (row >= NUv + NTv) return;
  const float* src;
  h16* dst;
  if (row < NUv) {
    src = eu + (size_t)xu[row] * Hv;
    dst = hu + (size_t)row * Hv;
  } else {
    int r2 = row - NUv;
    src = et + (size_t)xt[r2] * Hv;
    dst = ht + (size_t)r2 * Hv;
  }
  float4 v0 = *(const float4*)(src + c);
  float4 v1 = *(const float4*)(src + c + 4);
  f16x8 o;
  o[0] = (h16)v0.x; o[1] = (h16)v0.y; o[2] = (h16)v0.z; o[3] = (h16)v0.w;
  o[4] = (h16)v1.x; o[5] = (h16)v1.y; o[6] = (h16)v1.z; o[7] = (h16)v1.w;
  *(f16x8*)(dst + c) = o;
}

// --------------------------------------------------- fused gather+GEMM+bn
// OUT = relu(bn(seg_mean(SRC via off/ss) @ BTl + DENSE @ BTr + bl))
// mfma_f32_16x16x32_f16 convention (learn_hip m89):
//   A frag: a[j] = A[lane&15][kblk*32 + (lane>>4)*8 + j]
//   B frag: b[j] = B[kblk*32 + (lane>>4)*8 + j][lane&15]  (B^T stored [N][K])
//   D frag: d[r] = D[(lane>>4)*4 + r][lane&15]
__global__ __launch_bounds__(512, 8) void k_fused(const h16* __restrict__ SRC,
                                                  const h16* __restrict__ DENSE,
                                                  const int* __restrict__ off,
                                                  const int* __restrict__ ss,
                                                  const h16* __restrict__ BTl,
                                                  const h16* __restrict__ BTr,
                                                  const float* __restrict__ bl,
                                                  const float* __restrict__ sc,
                                                  const float* __restrict__ sh,
                                                  h16* __restrict__ C, int M) {
  __shared__ __align__(16) unsigned char smem[128 * 256];  // 32 KB
  int t = threadIdx.x;
  int blockBase = blockIdx.x * 128;
  int w = t >> 6, l = t & 63;
  int lm = l & 15, lk = l >> 4;
  int rowBase = blockBase + w * 16;

  // ---- early dense A loads (overlap their latency with the gather stage)
  int ar = imin(rowBase + lm, M - 1);
  const h16* arow = DENSE + (size_t)ar * Hv;
  f16x8 ad0 = *(const f16x8*)(arow + 0 * 32 + lk * 8);
  f16x8 ad1 = *(const f16x8*)(arow + 1 * 32 + lk * 8);
  f16x8 ad2 = *(const f16x8*)(arow + 2 * 32 + lk * 8);
  f16x8 ad3 = *(const f16x8*)(arow + 3 * 32 + lk * 8);

  // ---- stage: A1[128][128]f16 = seg_mean(SRC), two 64-row passes,
  //      8 threads/row x 16 cols (facc[16] keeps VGPR under the 64 cap)
#pragma unroll
  for (int half = 0; half < 2; half++) {
    int r = (t >> 3) + half * 64;
    int cs = (t & 7) * 16;
    float facc[16];
#pragma unroll
    for (int j = 0; j < 16; j++) facc[j] = 0.f;
    int row = blockBase + r;
    if (row < M) {
      int e0 = off[row], e1 = off[row + 1];
      for (int e = e0; e < e1; e++) {
        const f16x8* sp = (const f16x8*)(SRC + (size_t)ss[e] * Hv + cs);
        f16x8 v0 = sp[0], v1 = sp[1];
#pragma unroll
        for (int j = 0; j < 8; j++) {
          facc[j] += (float)v0[j];
          facc[8 + j] += (float)v1[j];
        }
      }
      int deg = e1 - e0;
      float inv = 1.f / (float)(deg > 1 ? deg : 1);
#pragma unroll
      for (int j = 0; j < 16; j++) facc[j] *= inv;
    }
#pragma unroll
    for (int q = 0; q < 2; q++) {
      f16x8 ov;
#pragma unroll
      for (int j = 0; j < 8; j++) ov[j] = (h16)facc[q * 8 + j];
      int byte = (r * 256 + cs * 2 + q * 16) ^ ((r & 7) << 4);
      *(f16x8*)(smem + byte) = ov;
    }
  }

  // ---- dense MFMA (pre-barrier: registers + L2-resident B only)
  f32x4 acc[8];
#pragma unroll
  for (int nf = 0; nf < 8; nf++) acc[nf] = (f32x4){0.f, 0.f, 0.f, 0.f};
#pragma unroll
  for (int nf = 0; nf < 8; nf++) {
    const h16* bp = BTr + (size_t)(nf * 16 + lm) * Hv + lk * 8;
    acc[nf] = __builtin_amdgcn_mfma_f32_16x16x32_f16(ad0, *(const f16x8*)(bp + 0), acc[nf], 0, 0, 0);
    acc[nf] = __builtin_amdgcn_mfma_f32_16x16x32_f16(ad1, *(const f16x8*)(bp + 32), acc[nf], 0, 0, 0);
    acc[nf] = __builtin_amdgcn_mfma_f32_16x16x32_f16(ad2, *(const f16x8*)(bp + 64), acc[nf], 0, 0, 0);
    acc[nf] = __builtin_amdgcn_mfma_f32_16x16x32_f16(ad3, *(const f16x8*)(bp + 96), acc[nf], 0, 0, 0);
  }
  __syncthreads();

  // ---- agg MFMA from LDS
#pragma unroll
  for (int s = 0; s < 4; s++) {
    int byteA = ((w * 16 + lm) * 256 + s * 64 + lk * 16) ^ ((lm & 7) << 4);
    f16x8 a = *(const f16x8*)(smem + byteA);
#pragma unroll
    for (int nf = 0; nf < 8; nf++) {
      f16x8 b = *(const f16x8*)(BTl + (size_t)(nf * 16 + lm) * Hv + s * 32 + lk * 8);
      acc[nf] = __builtin_amdgcn_mfma_f32_16x16x32_f16(a, b, acc[nf], 0, 0, 0);
    }
  }
  __syncthreads();  // A1 tile dead; reuse smem for out-tile

  // ---- epilogue: bn/relu, stage to LDS (swizzled), coalesced stores
#pragma unroll
  for (int nf = 0; nf < 8; nf++) {
    int col = nf * 16 + lm;
    float blv = bl[col], scv = sc[col], shv = sh[col];
#pragma unroll
    for (int r_ = 0; r_ < 4; r_++) {
      float x = fmaf(acc[nf][r_] + blv, scv, shv);
      h16 hv = (h16)fmaxf(x, 0.f);
      int rowl = w * 16 + lk * 4 + r_;
      int byte = (rowl * 256 + col * 2) ^ ((rowl & 7) << 4);
      *(h16*)(smem + byte) = hv;
    }
  }
  __syncthreads();
  {
    int r = t >> 2, cs = (t & 3) * 32;
    int row = blockBase + r;
    if (row < M) {
#pragma unroll
      for (int q = 0; q < 4; q++) {
        int byte = (r * 256 + cs * 2 + q * 16) ^ ((r & 7) << 4);
        f16x8 v = *(const f16x8*)(smem + byte);
        *(f16x8*)(C + (size_t)row * Hv + cs + q * 8) = v;
      }
    }
  }
}

// out = relu(h @ W1 + b1) @ W2 + b2, h = [h_u ; h_t] virtual concat
__global__ __launch_bounds__(512, 8) void k_mlp(const h16* __restrict__ HU,
                                                const h16* __restrict__ HT,
                                                const h16* __restrict__ W1T,
                                                const float* __restrict__ b1,
                                                const float* __restrict__ W2,
                                                const float* __restrict__ b2,
                                                float* __restrict__ out, int Mtot) {
  __shared__ float y[128][65];  // 33280 B
  int t = threadIdx.x;
  int w = t >> 6, l = t & 63;
  int lm = l & 15, lk = l >> 4;
  int rowBase = blockIdx.x * 128 + w * 16;
  int ar = imin(rowBase + lm, Mtot - 1);
  const h16* arow =
      (ar < NUv) ? (HU + (size_t)ar * Hv) : (HT + (size_t)(ar - NUv) * Hv);
  f32x4 acc[4];
#pragma unroll
  for (int nf = 0; nf < 4; nf++) acc[nf] = (f32x4){0.f, 0.f, 0.f, 0.f};
#pragma unroll
  for (int s = 0; s < 4; s++) {
    f16x8 a = *(const f16x8*)(arow + s * 32 + lk * 8);
#pragma unroll
    for (int nf = 0; nf < 4; nf++) {
      f16x8 b = *(const f16x8*)(W1T + (size_t)(nf * 16 + lm) * Hv + s * 32 + lk * 8);
      acc[nf] = __builtin_amdgcn_mfma_f32_16x16x32_f16(a, b, acc[nf], 0, 0, 0);
    }
  }
#pragma unroll
  for (int nf = 0; nf < 4; nf++) {
    int col = nf * 16 + lm;
    float b1v = b1[col];
#pragma unroll
    for (int r = 0; r < 4; r++) {
      int rloc = w * 16 + lk * 4 + r;
      y[rloc][col] = fmaxf(acc[nf][r] + b1v, 0.f);
    }
  }
  __syncthreads();
  if (t < 256) {
    int rloc = t >> 1, o = t & 1;
    int row = blockIdx.x * 128 + rloc;
    if (row < Mtot) {
      float sum = b2[o];
#pragma unroll
      for (int k = 0; k < HID2v; k++) sum += y[rloc][k] * W2[k * 2 + o];
      out[(size_t)row * 2 + o] = sum;
    }
  }
}

// ---------------------------------------------------------------- launcher
extern "C" void kernel_launch(void* const* d_in, const int* in_sizes, int n_in,
                              void* d_out, int out_size, void* d_ws, size_t ws_size,
                              hipStream_t stream) {
  (void)in_sizes; (void)n_in; (void)out_size;

  const int* x_user  = (const int*)d_in[0];
  const int* x_txn   = (const int*)d_in[1];
  const int* ei0_src = (const int*)d_in[2];
  const int* ei0_dst = (const int*)d_in[3];
  const int* ei1_src = (const int*)d_in[4];
  const int* ei1_dst = (const int*)d_in[5];
  const float* emb_user = (const float*)d_in[6];
  const float* emb_txn  = (const float*)d_in[7];
  const float* Wl = (const float*)d_in[8];
  const float* bl = (const float*)d_in[9];
  const float* Wr = (const float*)d_in[10];
  const float* bn_g = (const float*)d_in[11];
  const float* bn_b = (const float*)d_in[12];
  const float* bn_m = (const float*)d_in[13];
  const float* bn_v = (const float*)d_in[14];
  const float* W1 = (const float*)d_in[15];
  const float* b1 = (const float*)d_in[16];
  const float* W2 = (const float*)d_in[17];
  const float* b2 = (const float*)d_in[18];
  float* out = (float*)d_out;

  char* wsb;
  if (ws_size >= (size_t)WS_NEED) {
    wsb = (char*)d_ws;
  } else {
    void* sym = nullptr;
    hipGetSymbolAddress(&sym, HIP_SYMBOL(g_ws));
    wsb = (char*)sym;
  }
  size_t o = 0;
  auto alloc = [&](size_t bytes) -> void* {
    o = (o + 255) & ~(size_t)255;
    void* p = wsb + o;
    o += bytes;
    return p;
  };
  h16* hu   = (h16*)alloc((size_t)NUv * Hv * 2);   // in place
  h16* ht0  = (h16*)alloc((size_t)NTv * Hv * 2);   // double-buffered
  h16* ht1  = (h16*)alloc((size_t)NTv * Hv * 2);
  h16* WlT  = (h16*)alloc((size_t)NLv * 2 * Hv * Hv * 2);
  h16* WrT  = (h16*)alloc((size_t)NLv * 2 * Hv * Hv * 2);
  h16* W1T  = (h16*)alloc((size_t)HID2v * Hv * 2);
  float* bnsc = (float*)alloc((size_t)NLv * 2 * Hv * 4);
  float* bnsh = (float*)alloc((size_t)NLv * 2 * Hv * 4);
  int* off0 = (int*)alloc((size_t)(NTv + 1) * 4);
  int* off1 = (int*)alloc((size_t)(NUv + 1) * 4);
  int* cur0 = (int*)alloc((size_t)NTv * 4);
  int* cur1 = (int*)alloc((size_t)NUv * 4);
  int* ss0  = (int*)alloc((size_t)Ev * 4);
  int* ss1  = (int*)alloc((size_t)Ev * 4);
  int* bs0  = (int*)alloc(256 * 4);
  int* bs1  = (int*)alloc(256 * 4);

  const int G_E    = (Ev + 255) / 256;
  const int G_BS0  = (NTv + 2047) / 2048;        // 196
  const int G_BS1  = (NUv + 2047) / 2048;        // 49
  const int G_EMB  = ((NUv + NTv) * 16 + 255) / 256;
  const int G_WT   = (NLv * 2 * Hv * Hv + HID2v * Hv + 255) / 256;
  const int G_T    = (NTv + 127) / 128;          // 3125
  const int G_U    = (NUv + 127) / 128;          // 782
  const int G_MLP  = (NUv + NTv + 127) / 128;    // 3907

  // 1. CSR build
  hipMemsetAsync(cur0, 0, (size_t)NTv * 4, stream);
  hipMemsetAsync(cur1, 0, (size_t)NUv * 4, stream);
  k_count<<<G_E, 256, 0, stream>>>(ei0_dst, ei1_dst, cur0, cur1, Ev);
  k_blocksum<<<G_BS0, 256, 0, stream>>>(cur0, bs0, NTv);
  k_blocksum<<<G_BS1, 256, 0, stream>>>(cur1, bs1, NUv);
  k_scansmall<<<1, 256, 0, stream>>>(bs0, G_BS0);
  k_scansmall<<<1, 256, 0, stream>>>(bs1, G_BS1);
  k_scanfinal<<<G_BS0, 256, 0, stream>>>(cur0, bs0, off0, cur0, NTv);
  k_scanfinal<<<G_BS1, 256, 0, stream>>>(cur1, bs1, off1, cur1, NUv);
  k_fill<<<G_E, 256, 0, stream>>>(ei0_src, ei0_dst, ei1_src, ei1_dst,
                                  cur0, cur1, ss0, ss1, Ev);

  // 2. weight conversion + bn prep
  k_wt<<<G_WT, 256, 0, stream>>>(Wl, Wr, W1, WlT, WrT, W1T);
  k_bn<<<3, 256, 0, stream>>>(bn_g, bn_b, bn_m, bn_v, bnsc, bnsh);

  // 3. embedding gather
  k_embed<<<G_EMB, 256, 0, stream>>>(x_user, x_txn, emb_user, emb_txn, hu, ht0);

  // 4. layers
  h16* ht_cur = ht0; h16* ht_nxt = ht1;
  for (int i = 0; i < NLv; i++) {
    const h16* WlT0 = WlT + (size_t)(i * 2 + 0) * Hv * Hv;
    const h16* WlT1 = WlT + (size_t)(i * 2 + 1) * Hv * Hv;
    const h16* WrT0 = WrT + (size_t)(i * 2 + 0) * Hv * Hv;
    const h16* WrT1 = WrT + (size_t)(i * 2 + 1) * Hv * Hv;
    const float* bl0 = bl + (size_t)(i * 2 + 0) * Hv;
    const float* bl1 = bl + (size_t)(i * 2 + 1) * Hv;
    const float* sc0 = bnsc + (size_t)(i * 2 + 0) * Hv;
    const float* sh0 = bnsh + (size_t)(i * 2 + 0) * Hv;
    const float* sc1 = bnsc + (size_t)(i * 2 + 1) * Hv;
    const float* sh1 = bnsh + (size_t)(i * 2 + 1) * Hv;

    // h_t' : agg over CSR0 (src=hu), dense=ht_cur -> ht_nxt ; bn[i,1], bl[i,0]
    k_fused<<<G_T, 512, 0, stream>>>(hu, ht_cur, off0, ss0, WlT0, WrT0,
                                     bl0, sc1, sh1, ht_nxt, NTv);
    // h_u' : agg over CSR1 (src=ht_cur OLD), dense=hu -> hu ; bn[i,0], bl[i,1]
    k_fused<<<G_U, 512, 0, stream>>>(ht_cur, hu, off1, ss1, WlT1, WrT1,
                                     bl1, sc0, sh0, hu, NUv);
    h16* tmp = ht_cur; ht_cur = ht_nxt; ht_nxt = tmp;
  }

  // 5. MLP head
  k_mlp<<<G_MLP, 512, 0, stream>>>(hu, ht_cur, W1T, b1, W2, b2, out, NUv + NTv);
}

// Round 5
// 695.444 us; speedup vs baseline: 2.1096x; 2.1096x over previous
//
#include <hip/hip_runtime.h>

// ---------------------------------------------------------------------------
// HeteroFraudGNN on MI355X — round 5: kill address divergence + spills.
// Diagnosis history: r2 dense GEMM 1.5TB/s, r3 fused 0.86TB/s, all pipes <12%
// -> latency-bound on 16-line-divergent vmem loads (B-frags re-read 32KB of
// L2 per WAVE). r4's launch_bounds(512,8) capped regs at 64 -> spills
// (WRITE_SIZE 100->365MB).
// Fix: canonical LDS-staged GEMM. B staged coalesced into swizzled LDS once
// per block (2 phases: BTr then BTl, 32KB each); A-gather tile in swizzled
// LDS; fragments via ds_read_b128 at the b128 bank floor. launch_bounds(512,4).
//   LDS: sA 32KB (gather tile / epilogue out-tile) + sB 32KB = 64KB -> 2 blk/CU.
//   P0: issue BTr->regs, dense A-frags->regs; gather seg_mean -> sA; write sB. bar
//   P1: issue BTl->regs; dense MFMA (ad x sB). bar
//   P2: write sB=BTl. bar
//   P3: agg MFMA (sA x sB). bar
//   P4: bn/relu -> sA -> coalesced f16x8 stores.
// ---------------------------------------------------------------------------

#define NUv   100000
#define NTv   400000
#define Ev    400000
#define Hv    128
#define NLv   3
#define HID2v 64
#define EPSv  1e-5f

typedef _Float16 h16;
typedef __attribute__((ext_vector_type(8))) _Float16 f16x8;
typedef __attribute__((ext_vector_type(4))) float    f32x4;

#define WS_NEED (280u * 1024u * 1024u)
__device__ __attribute__((aligned(256))) static unsigned char g_ws[WS_NEED];

__device__ __forceinline__ int imin(int a, int b) { return a < b ? a : b; }
// swizzled byte offset inside a [n][128] h16 LDS tile (256B rows)
__device__ __forceinline__ int swz(int n, int kbyte) {
  return n * 256 + (kbyte ^ ((n & 7) << 4));
}

// ---------------------------------------------------------------- CSR build
__global__ __launch_bounds__(256) void k_count(const int* __restrict__ d0,
                                               const int* __restrict__ d1,
                                               int* __restrict__ c0,
                                               int* __restrict__ c1, int e) {
  int t = blockIdx.x * 256 + threadIdx.x;
  if (t < e) {
    atomicAdd(c0 + d0[t], 1);
    atomicAdd(c1 + d1[t], 1);
  }
}

__global__ __launch_bounds__(256) void k_blocksum(const int* __restrict__ cnt,
                                                  int* __restrict__ bs, int n) {
  __shared__ int red[256];
  int base = blockIdx.x * 2048 + threadIdx.x * 8;
  int s = 0;
#pragma unroll
  for (int j = 0; j < 8; j++) {
    int p = base + j;
    if (p < n) s += cnt[p];
  }
  red[threadIdx.x] = s;
  __syncthreads();
  for (int st = 128; st > 0; st >>= 1) {
    if (threadIdx.x < st) red[threadIdx.x] += red[threadIdx.x + st];
    __syncthreads();
  }
  if (threadIdx.x == 0) bs[blockIdx.x] = red[0];
}

__global__ __launch_bounds__(256) void k_scansmall(int* __restrict__ bs, int g) {
  __shared__ int lds[256];
  int t = threadIdx.x;
  int v = (t < g) ? bs[t] : 0;
  lds[t] = v;
  __syncthreads();
  for (int st = 1; st < 256; st <<= 1) {
    int x = (t >= st) ? lds[t - st] : 0;
    __syncthreads();
    lds[t] += x;
    __syncthreads();
  }
  if (t < g) bs[t] = lds[t] - v;  // exclusive
}

__global__ __launch_bounds__(256) void k_scanfinal(const int* __restrict__ cnt,
                                                   const int* __restrict__ bs,
                                                   int* __restrict__ off,
                                                   int* __restrict__ cur, int n) {
  __shared__ int lds[256];
  int t = threadIdx.x;
  int base = blockIdx.x * 2048 + t * 8;
  int v[8], pre[8];
  int tsum = 0;
#pragma unroll
  for (int j = 0; j < 8; j++) {
    int p = base + j;
    v[j] = (p < n) ? cnt[p] : 0;
    pre[j] = tsum;
    tsum += v[j];
  }
  lds[t] = tsum;
  __syncthreads();
  for (int st = 1; st < 256; st <<= 1) {
    int x = (t >= st) ? lds[t - st] : 0;
    __syncthreads();
    lds[t] += x;
    __syncthreads();
  }
  int texcl = lds[t] - tsum;
  int boff = bs[blockIdx.x];
#pragma unroll
  for (int j = 0; j < 8; j++) {
    int p = base + j;
    if (p < n) {
      int o = boff + texcl + pre[j];
      off[p] = o;
      cur[p] = o;
      if (p == n - 1) off[n] = o + v[j];
    }
  }
}

__global__ __launch_bounds__(256) void k_fill(const int* __restrict__ s0,
                                              const int* __restrict__ d0,
                                              const int* __restrict__ s1,
                                              const int* __restrict__ d1,
                                              int* __restrict__ cur0,
                                              int* __restrict__ cur1,
                                              int* __restrict__ ss0,
                                              int* __restrict__ ss1, int e) {
  int t = blockIdx.x * 256 + threadIdx.x;
  if (t < e) {
    int p = atomicAdd(cur0 + d0[t], 1);
    ss0[p] = s0[t];
    int q = atomicAdd(cur1 + d1[t], 1);
    ss1[q] = s1[t];
  }
}

// ------------------------------------------------------- weight / bn prep
__global__ __launch_bounds__(256) void k_wt(const float* __restrict__ Wl,
                                            const float* __restrict__ Wr,
                                            const float* __restrict__ W1,
                                            h16* __restrict__ WlT,
                                            h16* __restrict__ WrT,
                                            h16* __restrict__ W1T) {
  int t = blockIdx.x * 256 + threadIdx.x;
  const int NW = NLv * 2 * Hv * Hv;  // 196608
  if (t < NW) {
    int mat = t / (Hv * Hv);
    int n = (t / Hv) % Hv;
    int k = t % Hv;
    WlT[t] = (h16)Wl[(size_t)mat * Hv * Hv + (size_t)k * Hv + n];
    WrT[t] = (h16)Wr[(size_t)mat * Hv * Hv + (size_t)k * Hv + n];
  } else if (t < NW + HID2v * Hv) {
    int u = t - NW;
    int n = u / Hv;
    int k = u % Hv;
    W1T[u] = (h16)W1[(size_t)k * HID2v + n];
  }
}

__global__ __launch_bounds__(256) void k_bn(const float* __restrict__ g,
                                            const float* __restrict__ b,
                                            const float* __restrict__ m,
                                            const float* __restrict__ v,
                                            float* __restrict__ sc,
                                            float* __restrict__ sh) {
  int t = blockIdx.x * 256 + threadIdx.x;
  if (t < NLv * 2 * Hv) {
    float inv = rsqrtf(v[t] + EPSv);
    float s = g[t] * inv;
    sc[t] = s;
    sh[t] = b[t] - m[t] * s;
  }
}

// ------------------------------------------------------------- embeddings
__global__ __launch_bounds__(256) void k_embed(const int* __restrict__ xu,
                                               const int* __restrict__ xt,
                                               const float* __restrict__ eu,
                                               const float* __restrict__ et,
                                               h16* __restrict__ hu,
                                               h16* __restrict__ ht) {
  int t = blockIdx.x * 256 + threadIdx.x;
  int row = t >> 4;
  int c = (t & 15) * 8;
  if (row >= NUv + NTv) return;
  const float* src;
  h16* dst;
  if (row < NUv) {
    src = eu + (size_t)xu[row] * Hv;
    dst = hu + (size_t)row * Hv;
  } else {
    int r2 = row - NUv;
    src = et + (size_t)xt[r2] * Hv;
    dst = ht + (size_t)r2 * Hv;
  }
  float4 v0 = *(const float4*)(src + c);
  float4 v1 = *(const float4*)(src + c + 4);
  f16x8 o;
  o[0] = (h16)v0.x; o[1] = (h16)v0.y; o[2] = (h16)v0.z; o[3] = (h16)v0.w;
  o[4] = (h16)v1.x; o[5] = (h16)v1.y; o[6] = (h16)v1.z; o[7] = (h16)v1.w;
  *(f16x8*)(dst + c) = o;
}

// --------------------------------------------------- fused gather+GEMM+bn
// OUT = relu(bn(seg_mean(SRC via off/ss) @ BTl + DENSE @ BTr + bl))
// mfma_f32_16x16x32_f16 convention (learn_hip m89):
//   A frag: a[j] = A[lane&15][kblk*32 + (lane>>4)*8 + j]
//   B frag: b[j] = B[kblk*32 + (lane>>4)*8 + j][lane&15]  (B^T stored [N][K])
//   D frag: d[r] = D[(lane>>4)*4 + r][lane&15]
__global__ __launch_bounds__(512, 4) void k_fused(const h16* __restrict__ SRC,
                                                  const h16* __restrict__ DENSE,
                                                  const int* __restrict__ off,
                                                  const int* __restrict__ ss,
                                                  const h16* __restrict__ BTl,
                                                  const h16* __restrict__ BTr,
                                                  const float* __restrict__ bl,
                                                  const float* __restrict__ sc,
                                                  const float* __restrict__ sh,
                                                  h16* __restrict__ C, int M) {
  __shared__ __align__(16) unsigned char sA[128 * 256];  // 32 KB
  __shared__ __align__(16) unsigned char sB[128 * 256];  // 32 KB
  int t = threadIdx.x;
  int blockBase = blockIdx.x * 128;
  int w = t >> 6, l = t & 63;
  int lm = l & 15, lk = l >> 4;
  int rowBase = blockBase + w * 16;

  // ---- P0a: issue BTr -> regs (coalesced: thread t owns 32 h16 = 64B)
  const h16* bsrc = BTr + t * 32;
  f16x8 br0 = *(const f16x8*)(bsrc + 0);
  f16x8 br1 = *(const f16x8*)(bsrc + 8);
  f16x8 br2 = *(const f16x8*)(bsrc + 16);
  f16x8 br3 = *(const f16x8*)(bsrc + 24);

  // ---- P0b: issue dense A-frags (the only divergent loads left in GEMM)
  int ar = imin(rowBase + lm, M - 1);
  const h16* arow = DENSE + (size_t)ar * Hv;
  f16x8 ad0 = *(const f16x8*)(arow + 0 * 32 + lk * 8);
  f16x8 ad1 = *(const f16x8*)(arow + 1 * 32 + lk * 8);
  f16x8 ad2 = *(const f16x8*)(arow + 2 * 32 + lk * 8);
  f16x8 ad3 = *(const f16x8*)(arow + 3 * 32 + lk * 8);

  // ---- P0c: gather seg_mean -> sA (4 threads/row, 32 cols each, swizzled)
  {
    int r = t >> 2;
    int cs = (t & 3) * 32;
    float facc[32];
#pragma unroll
    for (int j = 0; j < 32; j++) facc[j] = 0.f;
    int row = blockBase + r;
    if (row < M) {
      int e0 = off[row], e1 = off[row + 1];
      for (int e = e0; e < e1; e++) {
        const f16x8* sp = (const f16x8*)(SRC + (size_t)ss[e] * Hv + cs);
#pragma unroll
        for (int q = 0; q < 4; q++) {
          f16x8 v = sp[q];
#pragma unroll
          for (int j = 0; j < 8; j++) facc[q * 8 + j] += (float)v[j];
        }
      }
      int deg = e1 - e0;
      float inv = 1.f / (float)(deg > 1 ? deg : 1);
#pragma unroll
      for (int j = 0; j < 32; j++) facc[j] *= inv;
    }
#pragma unroll
    for (int q = 0; q < 4; q++) {
      f16x8 ov;
#pragma unroll
      for (int j = 0; j < 8; j++) ov[j] = (h16)facc[q * 8 + j];
      *(f16x8*)(sA + swz(r, cs * 2 + q * 16)) = ov;
    }
  }

  // ---- P0d: write BTr regs -> sB (swizzled)
  {
    int n = (t * 32) >> 7;               // = t/4
    int kb = ((t * 32) & 127) * 2;       // 0,64,128,192
    *(f16x8*)(sB + swz(n, kb + 0)) = br0;
    *(f16x8*)(sB + swz(n, kb + 16)) = br1;
    // next 16 h16 may cross into next n? t*32+16: same n (32 h16 within 128-col row, kb+32 <= 192+... )
    *(f16x8*)(sB + swz(n, kb + 32)) = br2;   // wait: kb max 192 -> kb+48=240 < 256 OK, same row
    *(f16x8*)(sB + swz(n, kb + 48)) = br3;
  }
  __syncthreads();

  // ---- P1: issue BTl -> regs, then dense MFMA from sB
  const h16* bsrc2 = BTl + t * 32;
  f16x8 bl0 = *(const f16x8*)(bsrc2 + 0);
  f16x8 bl1 = *(const f16x8*)(bsrc2 + 8);
  f16x8 bl2 = *(const f16x8*)(bsrc2 + 16);
  f16x8 bl3 = *(const f16x8*)(bsrc2 + 24);

  f32x4 acc[8];
#pragma unroll
  for (int nf = 0; nf < 8; nf++) acc[nf] = (f32x4){0.f, 0.f, 0.f, 0.f};
  {
    f16x8 ads[4] = {ad0, ad1, ad2, ad3};
#pragma unroll
    for (int s = 0; s < 4; s++) {
#pragma unroll
      for (int nf = 0; nf < 8; nf++) {
        f16x8 b = *(const f16x8*)(sB + swz(nf * 16 + lm, s * 64 + lk * 16));
        acc[nf] = __builtin_amdgcn_mfma_f32_16x16x32_f16(ads[s], b, acc[nf], 0, 0, 0);
      }
    }
  }
  __syncthreads();  // all waves done reading sB(BTr)

  // ---- P2: write BTl regs -> sB
  {
    int n = (t * 32) >> 7;
    int kb = ((t * 32) & 127) * 2;
    *(f16x8*)(sB + swz(n, kb + 0)) = bl0;
    *(f16x8*)(sB + swz(n, kb + 16)) = bl1;
    *(f16x8*)(sB + swz(n, kb + 32)) = bl2;
    *(f16x8*)(sB + swz(n, kb + 48)) = bl3;
  }
  __syncthreads();

  // ---- P3: agg MFMA: sA frags x sB frags
#pragma unroll
  for (int s = 0; s < 4; s++) {
    f16x8 a = *(const f16x8*)(sA + swz(w * 16 + lm, s * 64 + lk * 16));
#pragma unroll
    for (int nf = 0; nf < 8; nf++) {
      f16x8 b = *(const f16x8*)(sB + swz(nf * 16 + lm, s * 64 + lk * 16));
      acc[nf] = __builtin_amdgcn_mfma_f32_16x16x32_f16(a, b, acc[nf], 0, 0, 0);
    }
  }
  __syncthreads();  // sA free for epilogue reuse

  // ---- P4: epilogue: bn/relu -> sA (swizzled) -> coalesced stores
#pragma unroll
  for (int nf = 0; nf < 8; nf++) {
    int col = nf * 16 + lm;
    float blv = bl[col], scv = sc[col], shv = sh[col];
#pragma unroll
    for (int r_ = 0; r_ < 4; r_++) {
      float x = fmaf(acc[nf][r_] + blv, scv, shv);
      h16 hv = (h16)fmaxf(x, 0.f);
      int rowl = w * 16 + lk * 4 + r_;
      *(h16*)(sA + swz(rowl, col * 2)) = hv;
    }
  }
  __syncthreads();
  {
    int r = t >> 2, cs = (t & 3) * 32;
    int row = blockBase + r;
    if (row < M) {
#pragma unroll
      for (int q = 0; q < 4; q++) {
        f16x8 v = *(const f16x8*)(sA + swz(r, cs * 2 + q * 16));
        *(f16x8*)(C + (size_t)row * Hv + cs + q * 8) = v;
      }
    }
  }
}

// out = relu(h @ W1 + b1) @ W2 + b2, h = [h_u ; h_t] virtual concat
__global__ __launch_bounds__(512, 4) void k_mlp(const h16* __restrict__ HU,
                                                const h16* __restrict__ HT,
                                                const h16* __restrict__ W1T,
                                                const float* __restrict__ b1,
                                                const float* __restrict__ W2,
                                                const float* __restrict__ b2,
                                                float* __restrict__ out, int Mtot) {
  __shared__ float y[128][65];                       // 33280 B
  __shared__ __align__(16) unsigned char sW[64 * 256];  // 16 KB, swizzled
  int t = threadIdx.x;
  int w = t >> 6, l = t & 63;
  int lm = l & 15, lk = l >> 4;

  // stage W1T (8192 h16) coalesced: thread t owns 16 h16
  {
    const h16* src = W1T + t * 16;
    f16x8 w0 = *(const f16x8*)(src + 0);
    f16x8 w1 = *(const f16x8*)(src + 8);
    int n = (t * 16) >> 7;
    int kb = ((t * 16) & 127) * 2;
    *(f16x8*)(sW + swz(n, kb + 0)) = w0;
    *(f16x8*)(sW + swz(n, kb + 16)) = w1;
  }

  int rowBase = blockIdx.x * 128 + w * 16;
  int ar = imin(rowBase + lm, Mtot - 1);
  const h16* arow =
      (ar < NUv) ? (HU + (size_t)ar * Hv) : (HT + (size_t)(ar - NUv) * Hv);
  f16x8 a0 = *(const f16x8*)(arow + 0 * 32 + lk * 8);
  f16x8 a1 = *(const f16x8*)(arow + 1 * 32 + lk * 8);
  f16x8 a2 = *(const f16x8*)(arow + 2 * 32 + lk * 8);
  f16x8 a3 = *(const f16x8*)(arow + 3 * 32 + lk * 8);
  __syncthreads();

  f32x4 acc[4];
#pragma unroll
  for (int nf = 0; nf < 4; nf++) acc[nf] = (f32x4){0.f, 0.f, 0.f, 0.f};
  {
    f16x8 as[4] = {a0, a1, a2, a3};
#pragma unroll
    for (int s = 0; s < 4; s++) {
#pragma unroll
      for (int nf = 0; nf < 4; nf++) {
        f16x8 b = *(const f16x8*)(sW + swz(nf * 16 + lm, s * 64 + lk * 16));
        acc[nf] = __builtin_amdgcn_mfma_f32_16x16x32_f16(as[s], b, acc[nf], 0, 0, 0);
      }
    }
  }
#pragma unroll
  for (int nf = 0; nf < 4; nf++) {
    int col = nf * 16 + lm;
    float b1v = b1[col];
#pragma unroll
    for (int r = 0; r < 4; r++) {
      int rloc = w * 16 + lk * 4 + r;
      y[rloc][col] = fmaxf(acc[nf][r] + b1v, 0.f);
    }
  }
  __syncthreads();
  if (t < 256) {
    int rloc = t >> 1, o = t & 1;
    int row = blockIdx.x * 128 + rloc;
    if (row < Mtot) {
      float sum = b2[o];
#pragma unroll
      for (int k = 0; k < HID2v; k++) sum += y[rloc][k] * W2[k * 2 + o];
      out[(size_t)row * 2 + o] = sum;
    }
  }
}

// ---------------------------------------------------------------- launcher
extern "C" void kernel_launch(void* const* d_in, const int* in_sizes, int n_in,
                              void* d_out, int out_size, void* d_ws, size_t ws_size,
                              hipStream_t stream) {
  (void)in_sizes; (void)n_in; (void)out_size;

  const int* x_user  = (const int*)d_in[0];
  const int* x_txn   = (const int*)d_in[1];
  const int* ei0_src = (const int*)d_in[2];
  const int* ei0_dst = (const int*)d_in[3];
  const int* ei1_src = (const int*)d_in[4];
  const int* ei1_dst = (const int*)d_in[5];
  const float* emb_user = (const float*)d_in[6];
  const float* emb_txn  = (const float*)d_in[7];
  const float* Wl = (const float*)d_in[8];
  const float* bl = (const float*)d_in[9];
  const float* Wr = (const float*)d_in[10];
  const float* bn_g = (const float*)d_in[11];
  const float* bn_b = (const float*)d_in[12];
  const float* bn_m = (const float*)d_in[13];
  const float* bn_v = (const float*)d_in[14];
  const float* W1 = (const float*)d_in[15];
  const float* b1 = (const float*)d_in[16];
  const float* W2 = (const float*)d_in[17];
  const float* b2 = (const float*)d_in[18];
  float* out = (float*)d_out;

  char* wsb;
  if (ws_size >= (size_t)WS_NEED) {
    wsb = (char*)d_ws;
  } else {
    void* sym = nullptr;
    hipGetSymbolAddress(&sym, HIP_SYMBOL(g_ws));
    wsb = (char*)sym;
  }
  size_t o = 0;
  auto alloc = [&](size_t bytes) -> void* {
    o = (o + 255) & ~(size_t)255;
    void* p = wsb + o;
    o += bytes;
    return p;
  };
  h16* hu   = (h16*)alloc((size_t)NUv * Hv * 2);   // in place
  h16* ht0  = (h16*)alloc((size_t)NTv * Hv * 2);   // double-buffered
  h16* ht1  = (h16*)alloc((size_t)NTv * Hv * 2);
  h16* WlT  = (h16*)alloc((size_t)NLv * 2 * Hv * Hv * 2);
  h16* WrT  = (h16*)alloc((size_t)NLv * 2 * Hv * Hv * 2);
  h16* W1T  = (h16*)alloc((size_t)HID2v * Hv * 2);
  float* bnsc = (float*)alloc((size_t)NLv * 2 * Hv * 4);
  float* bnsh = (float*)alloc((size_t)NLv * 2 * Hv * 4);
  int* off0 = (int*)alloc((size_t)(NTv + 1) * 4);
  int* off1 = (int*)alloc((size_t)(NUv + 1) * 4);
  int* cur0 = (int*)alloc((size_t)NTv * 4);
  int* cur1 = (int*)alloc((size_t)NUv * 4);
  int* ss0  = (int*)alloc((size_t)Ev * 4);
  int* ss1  = (int*)alloc((size_t)Ev * 4);
  int* bs0  = (int*)alloc(256 * 4);
  int* bs1  = (int*)alloc(256 * 4);

  const int G_E    = (Ev + 255) / 256;
  const int G_BS0  = (NTv + 2047) / 2048;        // 196
  const int G_BS1  = (NUv + 2047) / 2048;        // 49
  const int G_EMB  = ((NUv + NTv) * 16 + 255) / 256;
  const int G_WT   = (NLv * 2 * Hv * Hv + HID2v * Hv + 255) / 256;
  const int G_T    = (NTv + 127) / 128;          // 3125
  const int G_U    = (NUv + 127) / 128;          // 782
  const int G_MLP  = (NUv + NTv + 127) / 128;    // 3907

  // 1. CSR build
  hipMemsetAsync(cur0, 0, (size_t)NTv * 4, stream);
  hipMemsetAsync(cur1, 0, (size_t)NUv * 4, stream);
  k_count<<<G_E, 256, 0, stream>>>(ei0_dst, ei1_dst, cur0, cur1, Ev);
  k_blocksum<<<G_BS0, 256, 0, stream>>>(cur0, bs0, NTv);
  k_blocksum<<<G_BS1, 256, 0, stream>>>(cur1, bs1, NUv);
  k_scansmall<<<1, 256, 0, stream>>>(bs0, G_BS0);
  k_scansmall<<<1, 256, 0, stream>>>(bs1, G_BS1);
  k_scanfinal<<<G_BS0, 256, 0, stream>>>(cur0, bs0, off0, cur0, NTv);
  k_scanfinal<<<G_BS1, 256, 0, stream>>>(cur1, bs1, off1, cur1, NUv);
  k_fill<<<G_E, 256, 0, stream>>>(ei0_src, ei0_dst, ei1_src, ei1_dst,
                                  cur0, cur1, ss0, ss1, Ev);

  // 2. weight conversion + bn prep
  k_wt<<<G_WT, 256, 0, stream>>>(Wl, Wr, W1, WlT, WrT, W1T);
  k_bn<<<3, 256, 0, stream>>>(bn_g, bn_b, bn_m, bn_v, bnsc, bnsh);

  // 3. embedding gather
  k_embed<<<G_EMB, 256, 0, stream>>>(x_user, x_txn, emb_user, emb_txn, hu, ht0);

  // 4. layers
  h16* ht_cur = ht0; h16* ht_nxt = ht1;
  for (int i = 0; i < NLv; i++) {
    const h16* WlT0 = WlT + (size_t)(i * 2 + 0) * Hv * Hv;
    const h16* WlT1 = WlT + (size_t)(i * 2 + 1) * Hv * Hv;
    const h16* WrT0 = WrT + (size_t)(i * 2 + 0) * Hv * Hv;
    const h16* WrT1 = WrT + (size_t)(i * 2 + 1) * Hv * Hv;
    const float* bl0 = bl + (size_t)(i * 2 + 0) * Hv;
    const float* bl1 = bl + (size_t)(i * 2 + 1) * Hv;
    const float* sc0 = bnsc + (size_t)(i * 2 + 0) * Hv;
    const float* sh0 = bnsh + (size_t)(i * 2 + 0) * Hv;
    const float* sc1 = bnsc + (size_t)(i * 2 + 1) * Hv;
    const float* sh1 = bnsh + (size_t)(i * 2 + 1) * Hv;

    // h_t' : agg over CSR0 (src=hu), dense=ht_cur -> ht_nxt ; bn[i,1], bl[i,0]
    k_fused<<<G_T, 512, 0, stream>>>(hu, ht_cur, off0, ss0, WlT0, WrT0,
                                     bl0, sc1, sh1, ht_nxt, NTv);
    // h_u' : agg over CSR1 (src=ht_cur OLD), dense=hu -> hu ; bn[i,0], bl[i,1]
    k_fused<<<G_U, 512, 0, stream>>>(ht_cur, hu, off1, ss1, WlT1, WrT1,
                                     bl1, sc0, sh0, hu, NUv);
    h16* tmp = ht_cur; ht_cur = ht_nxt; ht_nxt = tmp;
  }

  // 5. MLP head
  k_mlp<<<G_MLP, 512, 0, stream>>>(hu, ht_cur, W1T, b1, W2, b2, out, NUv + NTv);
}